// Round 1
// baseline (11409.676 us; speedup 1.0000x reference)
//
#include <hip/hip_runtime.h>
#include <hip/hip_fp16.h>
#include <math.h>

constexpr int Bn = 8, Nn = 256, Dn = 768, Hn = 12, Kn = 128, Ln = 4;
constexpr int Tn = Nn * Bn;      // 2048 tokens
constexpr float SCALE = 0.125f;  // HD^-0.5, HD=64
constexpr float NEGB = -1e9f;

__device__ __forceinline__ float gelu_f(float x){
  return 0.5f * x * (1.0f + erff(x * 0.70710678118654752f));
}

__device__ __forceinline__ float wave_sum(float v){
#pragma unroll
  for (int off = 32; off; off >>= 1) v += __shfl_xor(v, off);
  return v;
}

// ---------------- Gaussian edge features: ef[b,i,k] = sum_j (!pad_j) gauss ----
__global__ __launch_bounds__(128) void ef_kernel(
    const int* __restrict__ atoms, const float* __restrict__ pos,
    const float* __restrict__ means, const float* __restrict__ stds,
    const float* __restrict__ gmul, const float* __restrict__ gbias,
    float* __restrict__ ef){
  int i = blockIdx.x, b = blockIdx.y;
  __shared__ float dist[Nn], ml[Nn], bs2[Nn];
  __shared__ int padm[Nn];
  int tid = threadIdx.x;
  int ai = atoms[b * Nn + i];
  float px = pos[(b * Nn + i) * 3], py = pos[(b * Nn + i) * 3 + 1], pz = pos[(b * Nn + i) * 3 + 2];
  for (int j = tid; j < Nn; j += 128){
    int aj = atoms[b * Nn + j];
    float dx = px - pos[(b * Nn + j) * 3];
    float dy = py - pos[(b * Nn + j) * 3 + 1];
    float dz = pz - pos[(b * Nn + j) * 3 + 2];
    float sq = dx * dx + dy * dy + dz * dz;
    dist[j] = sq > 0.f ? sqrtf(sq) : 0.f;
    int et = ai * 10 + aj;
    ml[j] = gmul[et];
    bs2[j] = gbias[et];
    padm[j] = (aj == 0);
  }
  __syncthreads();
  int k = tid;
  float mean = means[k];
  float sd = fabsf(stds[k]) + 1e-5f;
  float inv = 1.0f / sd;
  float cn = 1.0f / (sqrtf(2.0f * 3.14159f) * sd);
  float acc = 0.f;
  for (int j = 0; j < Nn; ++j){
    if (padm[j]) continue;
    float t = (ml[j] * dist[j] + bs2[j] - mean) * inv;
    acc += expf(-0.5f * t * t);
  }
  ef[(b * Nn + i) * Kn + k] = acc * cn;
}

// ---------------- attention bias: [B,H,N,N], gelu(gbf@W1+b1)@W2+b2, masked ----
__global__ __launch_bounds__(256) void bias_kernel(
    const int* __restrict__ atoms, const float* __restrict__ pos,
    const float* __restrict__ means, const float* __restrict__ stds,
    const float* __restrict__ gmul, const float* __restrict__ gbias,
    const float* __restrict__ w1, const float* __restrict__ b1,
    const float* __restrict__ w2, const float* __restrict__ b2,
    float* __restrict__ biasout){
  int i = blockIdx.x, b = blockIdx.y;
  __shared__ __half W1s[Kn * Kn];   // [kk][k2] 32 KB
  __shared__ __half GsT[Kn][72];    // [k][j]   18 KB (64 used, pad to 72)
  __shared__ float dist[Nn], ml[Nn], bs2[Nn];
  __shared__ int padm[Nn];
  int tid = threadIdx.x;
  for (int e = tid; e < Kn * Kn; e += 256) W1s[e] = __float2half(w1[e]);
  int ai = atoms[b * Nn + i];
  float px = pos[(b * Nn + i) * 3], py = pos[(b * Nn + i) * 3 + 1], pz = pos[(b * Nn + i) * 3 + 2];
  for (int j = tid; j < Nn; j += 256){
    int aj = atoms[b * Nn + j];
    float dx = px - pos[(b * Nn + j) * 3];
    float dy = py - pos[(b * Nn + j) * 3 + 1];
    float dz = pz - pos[(b * Nn + j) * 3 + 2];
    float sq = dx * dx + dy * dy + dz * dz;
    dist[j] = sq > 0.f ? sqrtf(sq) : 0.f;
    int et = ai * 10 + aj;
    ml[j] = gmul[et];
    bs2[j] = gbias[et];
    padm[j] = (aj == 0);
  }
  __syncthreads();
  int rq = tid >> 4, cg = tid & 15;
  int r0 = rq * 4, c0 = cg * 8;
  for (int jc = 0; jc < 4; ++jc){
    // phase A: gbf tile (transposed) for 64 j
    for (int e = tid; e < 64 * Kn; e += 256){
      int jj = e & 63, k = e >> 6;
      int j = jc * 64 + jj;
      float sd = fabsf(stds[k]) + 1e-5f;
      float t = (ml[j] * dist[j] + bs2[j] - means[k]) / sd;
      float g = expf(-0.5f * t * t) / (sqrtf(2.0f * 3.14159f) * sd);
      GsT[k][jj] = __float2half(g);
    }
    __syncthreads();
    // phase B: [64,128]@[128,128], micro 4x8 per thread
    float acc[4][8];
#pragma unroll
    for (int r = 0; r < 4; ++r)
#pragma unroll
      for (int c = 0; c < 8; ++c) acc[r][c] = 0.f;
#pragma unroll 4
    for (int kk = 0; kk < Kn; ++kk){
      float ar[4], wr[8];
      float2 f0 = __half22float2(*reinterpret_cast<const __half2*>(&GsT[kk][r0]));
      float2 f1 = __half22float2(*reinterpret_cast<const __half2*>(&GsT[kk][r0 + 2]));
      ar[0] = f0.x; ar[1] = f0.y; ar[2] = f1.x; ar[3] = f1.y;
      const __half2* wp = reinterpret_cast<const __half2*>(&W1s[kk * Kn + c0]);
#pragma unroll
      for (int q = 0; q < 4; ++q){
        float2 w = __half22float2(wp[q]);
        wr[2 * q] = w.x; wr[2 * q + 1] = w.y;
      }
#pragma unroll
      for (int r = 0; r < 4; ++r)
#pragma unroll
        for (int c = 0; c < 8; ++c) acc[r][c] += ar[r] * wr[c];
    }
#pragma unroll
    for (int r = 0; r < 4; ++r)
#pragma unroll
      for (int c = 0; c < 8; ++c) acc[r][c] = gelu_f(acc[r][c] + b1[c0 + c]);
    // phase C: @[128,12] via 16-lane shfl reduction
    for (int hh = 0; hh < Hn; ++hh){
      float w2r[8];
#pragma unroll
      for (int c = 0; c < 8; ++c) w2r[c] = w2[(c0 + c) * Hn + hh];
      for (int r = 0; r < 4; ++r){
        float s = 0.f;
#pragma unroll
        for (int c = 0; c < 8; ++c) s += acc[r][c] * w2r[c];
        s += __shfl_xor(s, 1); s += __shfl_xor(s, 2);
        s += __shfl_xor(s, 4); s += __shfl_xor(s, 8);
        if (cg == 0){
          int jg = jc * 64 + r0 + r;
          float v = padm[jg] ? NEGB : (s + b2[hh]);
          biasout[((b * Hn + hh) * Nn + i) * Nn + jg] = v;
        }
      }
    }
    __syncthreads();
  }
}

// ---------------- node = emb[atoms] + ef@edge_w + edge_b, written as [N,B,D] --
__global__ __launch_bounds__(256) void node_kernel(
    const int* __restrict__ atoms, const float* __restrict__ ef,
    const float* __restrict__ emb, const float* __restrict__ ew,
    const float* __restrict__ eb, float* __restrict__ nodeT){
  int n = blockIdx.x, b = blockIdx.y;
  __shared__ float efs[Kn];
  int tid = threadIdx.x;
  if (tid < Kn) efs[tid] = ef[(b * Nn + n) * Kn + tid];
  __syncthreads();
  int a = atoms[b * Nn + n];
  for (int d = tid; d < Dn; d += 256){
    float acc = emb[a * Dn + d] + eb[d];
#pragma unroll 8
    for (int k = 0; k < Kn; ++k) acc += efs[k] * ew[k * Dn + d];
    nodeT[(n * Bn + b) * Dn + d] = acc;
  }
}

// ---------------- generic fp32 GEMM: C = [res +] act(A@W + bias) --------------
template<int GELU, int RES>
__global__ __launch_bounds__(256) void gemm_kernel(
    const float* __restrict__ A, const float* __restrict__ W,
    const float* __restrict__ bias, const float* res, float* C,
    int M, int Kd, int Nd){
  __shared__ float As[32][68];  // [k][m] padded
  __shared__ float Ws[32][64];  // [k][n]
  int tid = threadIdx.x;
  int m0 = blockIdx.y * 64, n0 = blockIdx.x * 64;
  int row = (tid >> 4) << 2;
  int col = (tid & 15) << 2;
  float acc[16];
#pragma unroll
  for (int q = 0; q < 16; ++q) acc[q] = 0.f;
  for (int k0 = 0; k0 < Kd; k0 += 32){
    for (int e = tid; e < 64 * 32; e += 256){
      int r = e >> 5, c = e & 31;
      As[c][r] = A[(m0 + r) * Kd + k0 + c];
    }
    for (int e = tid; e < 32 * 64; e += 256){
      int r = e >> 6, c = e & 63;
      Ws[r][c] = W[(k0 + r) * Nd + n0 + c];
    }
    __syncthreads();
#pragma unroll
    for (int kk = 0; kk < 32; ++kk){
      float4 a = *reinterpret_cast<const float4*>(&As[kk][row]);
      float4 w = *reinterpret_cast<const float4*>(&Ws[kk][col]);
      acc[0]  += a.x * w.x; acc[1]  += a.x * w.y; acc[2]  += a.x * w.z; acc[3]  += a.x * w.w;
      acc[4]  += a.y * w.x; acc[5]  += a.y * w.y; acc[6]  += a.y * w.z; acc[7]  += a.y * w.w;
      acc[8]  += a.z * w.x; acc[9]  += a.z * w.y; acc[10] += a.z * w.z; acc[11] += a.z * w.w;
      acc[12] += a.w * w.x; acc[13] += a.w * w.y; acc[14] += a.w * w.z; acc[15] += a.w * w.w;
    }
    __syncthreads();
  }
#pragma unroll
  for (int r = 0; r < 4; ++r){
    int m = m0 + row + r;
#pragma unroll
    for (int c = 0; c < 4; ++c){
      int n = n0 + col + c;
      float v = acc[r * 4 + c] + bias[n];
      if (GELU) v = gelu_f(v);
      if (RES) v += res[m * Nd + n];
      C[m * Nd + n] = v;
    }
  }
}

// ---------------- LayerNorm over D=768; FINAL also transposes to [B,N,D] ------
template<int FINAL>
__global__ __launch_bounds__(256) void ln_kernel(
    const float* __restrict__ x, const float* __restrict__ sc,
    const float* __restrict__ bi, float* __restrict__ out){
  int t = blockIdx.x;
  int tid = threadIdx.x;
  const float* xr = x + t * Dn;
  float v0 = xr[tid], v1 = xr[tid + 256], v2 = xr[tid + 512];
  __shared__ float red[4];
  __shared__ float red2[4];
  float s = wave_sum(v0 + v1 + v2);
  if ((tid & 63) == 0) red[tid >> 6] = s;
  __syncthreads();
  float mean = (red[0] + red[1] + red[2] + red[3]) * (1.0f / 768.0f);
  float d0 = v0 - mean, d1 = v1 - mean, d2 = v2 - mean;
  float vs = wave_sum(d0 * d0 + d1 * d1 + d2 * d2);
  if ((tid & 63) == 0) red2[tid >> 6] = vs;
  __syncthreads();
  float var = (red2[0] + red2[1] + red2[2] + red2[3]) * (1.0f / 768.0f);
  float r = rsqrtf(var + 1e-5f);
  int ob;
  if (FINAL){
    int n = t >> 3, bb = t & 7;
    ob = (bb * Nn + n) * Dn;
  } else {
    ob = t * Dn;
  }
  out[ob + tid]       = d0 * r * sc[tid]       + bi[tid];
  out[ob + tid + 256] = d1 * r * sc[tid + 256] + bi[tid + 256];
  out[ob + tid + 512] = d2 * r * sc[tid + 512] + bi[tid + 512];
}

// ---------------- attention: one block per (b,h,32-row i-tile) ----------------
__global__ __launch_bounds__(256) void attn_kernel(
    const float* __restrict__ qkv, const float* __restrict__ biasb,
    float* __restrict__ out){
  int it = blockIdx.x, h = blockIdx.y, b = blockIdx.z;
  int i0 = it * 32;
  __shared__ float Qs[32][68];
  __shared__ float KVs[64][68];
  __shared__ float S[32][264];
  int tid = threadIdx.x;
  for (int e = tid; e < 32 * 64; e += 256){
    int ii = e >> 6, d = e & 63;
    Qs[ii][d] = qkv[((i0 + ii) * Bn + b) * (3 * Dn) + h * 64 + d] * SCALE;
  }
  int irow = tid >> 3, jg = tid & 7;
  for (int jt = 0; jt < 4; ++jt){
    __syncthreads();
    for (int e = tid; e < 64 * 64; e += 256){
      int jj = e >> 6, d = e & 63;
      KVs[jj][d] = qkv[((jt * 64 + jj) * Bn + b) * (3 * Dn) + Dn + h * 64 + d];
    }
    __syncthreads();
#pragma unroll
    for (int u = 0; u < 8; ++u){
      int jj = jg + (u << 3);
      float s = 0.f;
#pragma unroll
      for (int d4 = 0; d4 < 64; d4 += 4){
        float4 qv = *reinterpret_cast<const float4*>(&Qs[irow][d4]);
        float4 kv = *reinterpret_cast<const float4*>(&KVs[jj][d4]);
        s += qv.x * kv.x + qv.y * kv.y + qv.z * kv.z + qv.w * kv.w;
      }
      int j = (jt << 6) + jj;
      S[irow][j] = s + biasb[((b * Hn + h) * Nn + i0 + irow) * Nn + j];
    }
  }
  __syncthreads();
  // softmax, 8 threads per row
  float m = -1e30f;
  for (int u = 0; u < 32; ++u) m = fmaxf(m, S[irow][jg + (u << 3)]);
  m = fmaxf(m, __shfl_xor(m, 1)); m = fmaxf(m, __shfl_xor(m, 2)); m = fmaxf(m, __shfl_xor(m, 4));
  float sum = 0.f;
  for (int u = 0; u < 32; ++u){
    float p = expf(S[irow][jg + (u << 3)] - m);
    S[irow][jg + (u << 3)] = p;
    sum += p;
  }
  sum += __shfl_xor(sum, 1); sum += __shfl_xor(sum, 2); sum += __shfl_xor(sum, 4);
  float invs = 1.0f / sum;
  for (int u = 0; u < 32; ++u) S[irow][jg + (u << 3)] *= invs;
  // PV
  float o[8];
#pragma unroll
  for (int q = 0; q < 8; ++q) o[q] = 0.f;
  int dd0 = (tid & 7) << 3;
  for (int jt = 0; jt < 4; ++jt){
    __syncthreads();
    for (int e = tid; e < 64 * 64; e += 256){
      int jj = e >> 6, d = e & 63;
      KVs[jj][d] = qkv[((jt * 64 + jj) * Bn + b) * (3 * Dn) + 2 * Dn + h * 64 + d];
    }
    __syncthreads();
    for (int jj = 0; jj < 64; ++jj){
      float p = S[irow][(jt << 6) + jj];
      float4 v0 = *reinterpret_cast<const float4*>(&KVs[jj][dd0]);
      float4 v1 = *reinterpret_cast<const float4*>(&KVs[jj][dd0 + 4]);
      o[0] += p * v0.x; o[1] += p * v0.y; o[2] += p * v0.z; o[3] += p * v0.w;
      o[4] += p * v1.x; o[5] += p * v1.y; o[6] += p * v1.z; o[7] += p * v1.w;
    }
  }
#pragma unroll
  for (int q = 0; q < 8; ++q)
    out[((i0 + irow) * Bn + b) * Dn + h * 64 + dd0 + q] = o[q];
}

// =============================================================================
extern "C" void kernel_launch(void* const* d_in, const int* in_sizes, int n_in,
                              void* d_out, int out_size, void* d_ws, size_t ws_size,
                              hipStream_t stream){
  (void)in_sizes; (void)n_in; (void)out_size; (void)ws_size;
  const int*   atoms    = (const int*)  d_in[0];
  const float* pos      = (const float*)d_in[1];
  const float* atom_emb = (const float*)d_in[2];
  const float* gbf_means= (const float*)d_in[3];
  const float* gbf_stds = (const float*)d_in[4];
  const float* gbf_mul  = (const float*)d_in[5];
  const float* gbf_bias = (const float*)d_in[6];
  const float* bp_w1    = (const float*)d_in[7];
  const float* bp_b1    = (const float*)d_in[8];
  const float* bp_w2    = (const float*)d_in[9];
  const float* bp_b2    = (const float*)d_in[10];
  const float* edge_w   = (const float*)d_in[11];
  const float* edge_b   = (const float*)d_in[12];
  const float* ap_w     = (const float*)d_in[13];
  const float* ap_b     = (const float*)d_in[14];
  const float* ln1_s    = (const float*)d_in[15];
  const float* ln1_b    = (const float*)d_in[16];
  const float* wi       = (const float*)d_in[17];
  const float* bi       = (const float*)d_in[18];
  const float* wo       = (const float*)d_in[19];
  const float* bo       = (const float*)d_in[20];
  const float* ln2_s    = (const float*)d_in[21];
  const float* ln2_b    = (const float*)d_in[22];
  const float* w1       = (const float*)d_in[23];
  const float* b1       = (const float*)d_in[24];
  const float* w2       = (const float*)d_in[25];
  const float* b2       = (const float*)d_in[26];
  const float* fln_s    = (const float*)d_in[27];
  const float* fln_b    = (const float*)d_in[28];
  float* out = (float*)d_out;

  float* ws      = (float*)d_ws;
  float* biasbuf = ws;                              // B*H*N*N = 6,291,456
  float* xbuf    = biasbuf + Bn * Hn * Nn * Nn;     // T*D
  float* hbuf    = xbuf + Tn * Dn;                  // T*D
  float* qkv     = hbuf + Tn * Dn;                  // T*3D
  float* attn    = qkv + Tn * 3 * Dn;               // T*D
  float* efb     = attn + Tn * Dn;                  // B*N*K
  float* ffn     = qkv;                             // reuse qkv region for FFN mid

  dim3 gridNB(Nn, Bn);
  ef_kernel<<<gridNB, 128, 0, stream>>>(atoms, pos, gbf_means, gbf_stds, gbf_mul, gbf_bias, efb);
  bias_kernel<<<gridNB, 256, 0, stream>>>(atoms, pos, gbf_means, gbf_stds, gbf_mul, gbf_bias,
                                          bp_w1, bp_b1, bp_w2, bp_b2, biasbuf);
  node_kernel<<<gridNB, 256, 0, stream>>>(atoms, efb, atom_emb, edge_w, edge_b, hbuf);
  gemm_kernel<0,0><<<dim3(Dn / 64, Tn / 64), 256, 0, stream>>>(hbuf, ap_w, ap_b, nullptr, xbuf, Tn, Dn, Dn);

  for (int blk = 0; blk < 2; ++blk){
    for (int l = 0; l < Ln; ++l){
      ln_kernel<0><<<Tn, 256, 0, stream>>>(xbuf, ln1_s + l * Dn, ln1_b + l * Dn, hbuf);
      gemm_kernel<0,0><<<dim3(3 * Dn / 64, Tn / 64), 256, 0, stream>>>(
          hbuf, wi + (size_t)l * Dn * 3 * Dn, bi + l * 3 * Dn, nullptr, qkv, Tn, Dn, 3 * Dn);
      attn_kernel<<<dim3(Nn / 32, Hn, Bn), 256, 0, stream>>>(qkv, biasbuf, attn);
      gemm_kernel<0,1><<<dim3(Dn / 64, Tn / 64), 256, 0, stream>>>(
          attn, wo + (size_t)l * Dn * Dn, bo + l * Dn, xbuf, xbuf, Tn, Dn, Dn);
      ln_kernel<0><<<Tn, 256, 0, stream>>>(xbuf, ln2_s + l * Dn, ln2_b + l * Dn, hbuf);
      gemm_kernel<1,0><<<dim3(Dn / 64, Tn / 64), 256, 0, stream>>>(
          hbuf, w1 + (size_t)l * Dn * Dn, b1 + l * Dn, nullptr, ffn, Tn, Dn, Dn);
      gemm_kernel<0,1><<<dim3(Dn / 64, Tn / 64), 256, 0, stream>>>(
          ffn, w2 + (size_t)l * Dn * Dn, b2 + l * Dn, xbuf, xbuf, Tn, Dn, Dn);
    }
  }
  ln_kernel<1><<<Tn, 256, 0, stream>>>(xbuf, fln_s, fln_b, out);
}

// Round 2
// 957.158 us; speedup vs baseline: 11.9204x; 11.9204x over previous
//
#include <hip/hip_runtime.h>
#include <math.h>

constexpr int Bn = 8, Nn = 256, Dn = 768, Hn = 12, Kn = 128;
constexpr int Tn = Nn * Bn;      // 2048 tokens
constexpr float SCALE = 0.125f;  // HD^-0.5, HD=64
constexpr float NEGB = -1e9f;

typedef __attribute__((ext_vector_type(8))) short bf16x8;
typedef __attribute__((ext_vector_type(4))) float f32x4;

#define MFMA16(a, b, c) __builtin_amdgcn_mfma_f32_16x16x32_bf16((a), (b), (c), 0, 0, 0)

__device__ __forceinline__ void gload_lds16(const void* g, void* l) {
  __builtin_amdgcn_global_load_lds(
      (const __attribute__((address_space(1))) void*)g,
      (__attribute__((address_space(3))) void*)l, 16, 0, 0);
}

__device__ __forceinline__ ushort f2bf(float x) {
  union { float f; unsigned u; } v; v.f = x;
  unsigned r = (v.u + 0x7fff + ((v.u >> 16) & 1)) >> 16;
  return (ushort)r;
}
__device__ __forceinline__ float bf2f(ushort u) {
  union { unsigned u; float f; } v; v.u = ((unsigned)u) << 16;
  return v.f;
}
__device__ __forceinline__ float gelu_f(float x) {
  return 0.5f * x * (1.0f + erff(x * 0.70710678118654752f));
}
__device__ __forceinline__ float wave_sum(float v) {
#pragma unroll
  for (int off = 32; off; off >>= 1) v += __shfl_xor(v, off);
  return v;
}

// ---------------- weight transpose+convert: W[K,N] f32 -> WT[N,K] bf16 -------
__global__ __launch_bounds__(256) void wtrans(const float* __restrict__ W,
                                              ushort* __restrict__ WT,
                                              int Kd, int Nd) {
  __shared__ float tile[64][65];
  const float* Wl = W + (size_t)blockIdx.z * Kd * Nd;
  ushort* WTl = WT + (size_t)blockIdx.z * Kd * Nd;
  int n0 = blockIdx.x * 64, k0 = blockIdx.y * 64;
  int tid = threadIdx.x;
  for (int e = tid; e < 64 * 64; e += 256) {
    int r = e >> 6, c = e & 63;
    tile[r][c] = Wl[(size_t)(k0 + r) * Nd + n0 + c];
  }
  __syncthreads();
  for (int e = tid; e < 64 * 64; e += 256) {
    int r = e >> 6, c = e & 63;
    WTl[(size_t)(n0 + r) * Kd + k0 + c] = f2bf(tile[c][r]);
  }
}

// ---------------- Gaussian edge features: ef[b,i,k] = sum_j (!pad_j) gauss ----
__global__ __launch_bounds__(128) void ef_kernel(
    const int* __restrict__ atoms, const float* __restrict__ pos,
    const float* __restrict__ means, const float* __restrict__ stds,
    const float* __restrict__ gmul, const float* __restrict__ gbias,
    float* __restrict__ ef) {
  int i = blockIdx.x, b = blockIdx.y;
  __shared__ float dist[Nn], ml[Nn], bs2[Nn];
  __shared__ int padm[Nn];
  int tid = threadIdx.x;
  int ai = atoms[b * Nn + i];
  float px = pos[(b * Nn + i) * 3], py = pos[(b * Nn + i) * 3 + 1], pz = pos[(b * Nn + i) * 3 + 2];
  for (int j = tid; j < Nn; j += 128) {
    int aj = atoms[b * Nn + j];
    float dx = px - pos[(b * Nn + j) * 3];
    float dy = py - pos[(b * Nn + j) * 3 + 1];
    float dz = pz - pos[(b * Nn + j) * 3 + 2];
    float sq = dx * dx + dy * dy + dz * dz;
    dist[j] = sq > 0.f ? sqrtf(sq) : 0.f;
    int et = ai * 10 + aj;
    ml[j] = gmul[et];
    bs2[j] = gbias[et];
    padm[j] = (aj == 0);
  }
  __syncthreads();
  int k = tid;
  float mean = means[k];
  float sd = fabsf(stds[k]) + 1e-5f;
  float inv = 1.0f / sd;
  float cn = 1.0f / (sqrtf(2.0f * 3.14159f) * sd);
  float acc = 0.f;
  for (int j = 0; j < Nn; ++j) {
    if (padm[j]) continue;
    float t = (ml[j] * dist[j] + bs2[j] - mean) * inv;
    acc += expf(-0.5f * t * t);
  }
  ef[(b * Nn + i) * Kn + k] = acc * cn;
}

// ---------------- bias MLP via MFMA: gelu(gbf@W1+b1)@W2+b2 -> [B,H,N,N] bf16 --
__global__ __launch_bounds__(256, 2) void gbias_kernel(
    const int* __restrict__ atoms, const float* __restrict__ pos,
    const float* __restrict__ means, const float* __restrict__ stds,
    const float* __restrict__ gmul, const float* __restrict__ gbias_,
    const ushort* __restrict__ w1T, const float* __restrict__ b1,
    const float* __restrict__ w2, const float* __restrict__ b2,
    ushort* __restrict__ biasb) {
  int jt = blockIdx.x, i = blockIdx.y, b = blockIdx.z;
  int j0 = jt * 64;
  __shared__ char Ag[16384];     // [64 rows j][128 k] bf16, XOR-swizzled (256B rows)
  __shared__ char W1s[32768];    // [128 n][128 k] bf16, XOR-swizzled
  __shared__ float W2s[128 * 12];
  __shared__ float dls[64], mll[64], bsl[64];
  __shared__ int pml[64];
  __shared__ float mns[128], sds[128], cns[128], b1s[128];
  int tid = threadIdx.x, w = tid >> 6, ln = tid & 63;
  // stage W1T via global_load_lds (pre-swizzled source)
  {
    int srow = ln >> 4, sc = ln & 15;
#pragma unroll
    for (int q = 0; q < 8; ++q) {
      int inst = w * 8 + q;
      int row = inst * 4 + srow;
      const char* g = (const char*)(w1T + row * 128) + ((sc * 16) ^ ((row & 7) << 4));
      gload_lds16(g, W1s + inst * 1024);
    }
  }
  if (tid < 128) {
    mns[tid] = means[tid];
    float sd = fabsf(stds[tid]) + 1e-5f;
    sds[tid] = sd;
    cns[tid] = 1.0f / (sqrtf(2.0f * 3.14159f) * sd);
    b1s[tid] = b1[tid];
  }
  for (int e = tid; e < 128 * 12; e += 256) W2s[e] = w2[e];
  int ai = atoms[b * Nn + i];
  if (tid < 64) {
    int j = j0 + tid;
    int aj = atoms[b * Nn + j];
    float dx = pos[(b * Nn + i) * 3]     - pos[(b * Nn + j) * 3];
    float dy = pos[(b * Nn + i) * 3 + 1] - pos[(b * Nn + j) * 3 + 1];
    float dz = pos[(b * Nn + i) * 3 + 2] - pos[(b * Nn + j) * 3 + 2];
    float sq = dx * dx + dy * dy + dz * dz;
    dls[tid] = sq > 0.f ? sqrtf(sq) : 0.f;
    int et = ai * 10 + aj;
    mll[tid] = gmul[et];
    bsl[tid] = gbias_[et];
    pml[tid] = (aj == 0);
  }
  __syncthreads();
  // build Ag: gbf tile [64][128] bf16 swizzled
  for (int idx = tid; idx < 64 * 128; idx += 256) {
    int row = idx >> 7, k = idx & 127;
    float t = (mll[row] * dls[row] + bsl[row] - mns[k]) / sds[k];
    float g = expf(-0.5f * t * t) * cns[k];
    *(ushort*)(Ag + row * 256 + ((2 * k) ^ ((row & 7) << 4))) = f2bf(g);
  }
  __syncthreads();
  const int frow = ln & 15, fgrp = ln >> 4;
  int arow = w * 16 + frow;
  f32x4 acc[8] = {};
#pragma unroll
  for (int ks = 0; ks < 4; ++ks) {
    bf16x8 af = *(const bf16x8*)(Ag + arow * 256 + ((ks * 64 + fgrp * 16) ^ ((arow & 7) << 4)));
#pragma unroll
    for (int nt = 0; nt < 8; ++nt) {
      int brow = nt * 16 + frow;
      bf16x8 bfv = *(const bf16x8*)(W1s + brow * 256 + ((ks * 64 + fgrp * 16) ^ ((brow & 7) << 4)));
      acc[nt] = MFMA16(af, bfv, acc[nt]);
    }
  }
  float g[8][4];
#pragma unroll
  for (int nt = 0; nt < 8; ++nt)
#pragma unroll
    for (int r = 0; r < 4; ++r)
      g[nt][r] = gelu_f(acc[nt][r] + b1s[nt * 16 + frow]);
  // W2 [128,12] via per-lane partials + 16-lane shfl reduce
#pragma unroll
  for (int r = 0; r < 4; ++r) {
    int jloc = w * 16 + fgrp * 4 + r;
    float myv = 0.f;
#pragma unroll
    for (int h = 0; h < 12; ++h) {
      float s = 0.f;
#pragma unroll
      for (int nt = 0; nt < 8; ++nt) s += g[nt][r] * W2s[(nt * 16 + frow) * 12 + h];
      s += __shfl_xor(s, 1); s += __shfl_xor(s, 2);
      s += __shfl_xor(s, 4); s += __shfl_xor(s, 8);
      if (frow == h) myv = s;
    }
    if (frow < 12) {
      int j = j0 + jloc;
      float v = pml[jloc] ? NEGB : (myv + b2[frow]);
      biasb[(((size_t)b * Hn + frow) * Nn + i) * Nn + j] = f2bf(v);
    }
  }
}

// ---------------- node = emb[atoms] + ef@edge_w + edge_b -> [N,B,D] bf16 ------
__global__ __launch_bounds__(256) void node_kernel(
    const int* __restrict__ atoms, const float* __restrict__ ef,
    const float* __restrict__ emb, const float* __restrict__ ew,
    const float* __restrict__ eb, ushort* __restrict__ nodeT) {
  int n = blockIdx.x, b = blockIdx.y;
  __shared__ float efs[Kn];
  int tid = threadIdx.x;
  if (tid < Kn) efs[tid] = ef[(b * Nn + n) * Kn + tid];
  __syncthreads();
  int a = atoms[b * Nn + n];
  for (int d = tid; d < Dn; d += 256) {
    float acc = emb[a * Dn + d] + eb[d];
#pragma unroll 8
    for (int k = 0; k < Kn; ++k) acc += efs[k] * ew[k * Dn + d];
    nodeT[(size_t)(n * Bn + b) * Dn + d] = f2bf(acc);
  }
}

// ---------------- MFMA GEMM: A[M,K]bf16 @ WT[N,K]bf16 -----------------------
// MODE 0: bf16 out; 1: gelu bf16 out; 2: f32 out + residual; 3: f32 out
template <int MODE>
__global__ __launch_bounds__(256, 4) void mgemm(
    const ushort* __restrict__ A, const ushort* __restrict__ WT,
    const float* __restrict__ bias, const float* __restrict__ res,
    void* __restrict__ Cout, int M, int Kd, int Nd) {
  __shared__ char smem[16384];
  char* ldsA = smem;
  char* ldsB = smem + 8192;
  const int tid = threadIdx.x, w = tid >> 6, ln = tid & 63;
  const int m0 = blockIdx.y * 64, n0 = blockIdx.x * 64;
  const int wm = (w >> 1) * 32, wn = (w & 1) * 32;
  const int srow = ln >> 3, schunk = ln & 7;
  const int sswz = (schunk * 16) ^ (srow << 4);
  const int frow = ln & 15, fgrp = ln >> 4;
  f32x4 acc[2][2] = {};
  for (int kt = 0; kt < Kd; kt += 64) {
    __syncthreads();
#pragma unroll
    for (int q = 0; q < 2; ++q) {
      int r = (w * 2 + q) * 8 + srow;
      gload_lds16((const char*)(A + (size_t)(m0 + r) * Kd + kt) + sswz, ldsA + (w * 2 + q) * 1024);
    }
#pragma unroll
    for (int q = 0; q < 2; ++q) {
      int r = (w * 2 + q) * 8 + srow;
      gload_lds16((const char*)(WT + (size_t)(n0 + r) * Kd + kt) + sswz, ldsB + (w * 2 + q) * 1024);
    }
    __syncthreads();
#pragma unroll
    for (int ks = 0; ks < 2; ++ks) {
      bf16x8 af[2], bfv[2];
#pragma unroll
      for (int mt = 0; mt < 2; ++mt) {
        int row = wm + mt * 16 + frow;
        af[mt] = *(const bf16x8*)(ldsA + row * 128 + ((ks * 64 + fgrp * 16) ^ ((row & 7) << 4)));
      }
#pragma unroll
      for (int nt = 0; nt < 2; ++nt) {
        int row = wn + nt * 16 + frow;
        bfv[nt] = *(const bf16x8*)(ldsB + row * 128 + ((ks * 64 + fgrp * 16) ^ ((row & 7) << 4)));
      }
      acc[0][0] = MFMA16(af[0], bfv[0], acc[0][0]);
      acc[0][1] = MFMA16(af[0], bfv[1], acc[0][1]);
      acc[1][0] = MFMA16(af[1], bfv[0], acc[1][0]);
      acc[1][1] = MFMA16(af[1], bfv[1], acc[1][1]);
    }
  }
#pragma unroll
  for (int nt = 0; nt < 2; ++nt) {
    int n = n0 + wn + nt * 16 + frow;
    float bv = bias[n];
#pragma unroll
    for (int mt = 0; mt < 2; ++mt) {
#pragma unroll
      for (int r = 0; r < 4; ++r) {
        int m = m0 + wm + mt * 16 + fgrp * 4 + r;
        float v = acc[mt][nt][r] + bv;
        if (MODE == 1) v = gelu_f(v);
        if (MODE == 2) v += res[(size_t)m * Nd + n];
        if (MODE <= 1) ((ushort*)Cout)[(size_t)m * Nd + n] = f2bf(v);
        else           ((float*)Cout)[(size_t)m * Nd + n] = v;
      }
    }
  }
}

// ---------------- per-layer V transpose: qkv V section -> vT[b,h,d,j] bf16 ----
__global__ __launch_bounds__(256) void vtrans(const ushort* __restrict__ qkvb,
                                              ushort* __restrict__ vT) {
  int h = blockIdx.x, b = blockIdx.y;
  __shared__ ushort Vs[256][64];
  int tid = threadIdx.x;
  for (int idx = tid; idx < 2048; idx += 256) {
    int j = idx >> 3, ch = idx & 7;
    *(bf16x8*)&Vs[j][ch * 8] =
        *(const bf16x8*)(qkvb + (size_t)(j * 8 + b) * 2304 + 1536 + h * 64 + ch * 8);
  }
  __syncthreads();
  char* base = (char*)(vT + (size_t)((b * Hn + h) * 64) * 256);
  for (int idx = tid; idx < 2048; idx += 256) {
    int d = idx & 63, jc = idx >> 6;
    ushort tmp[8];
#pragma unroll
    for (int jj = 0; jj < 8; ++jj) tmp[jj] = Vs[jc * 8 + jj][d];
    *(bf16x8*)(base + d * 512 + jc * 16) = *(bf16x8*)tmp;
  }
}

// ---------------- MFMA attention: block = (b, h, 64 i-rows) -------------------
__global__ __launch_bounds__(256, 2) void attn_mfma(
    const ushort* __restrict__ qkv, const ushort* __restrict__ vT,
    const ushort* __restrict__ biasb, ushort* __restrict__ Oout) {
  int it = blockIdx.x, h = blockIdx.y, b = blockIdx.z;
  int i0 = it * 64;
  __shared__ char smem[65536];
  char* Ks = smem;           // [256 j][64 k] bf16 swizzled; later P[4][16][256]
  char* Vs = smem + 32768;   // [64 d][256 j] bf16 swizzled (V^T)
  const int tid = threadIdx.x, w = tid >> 6, ln = tid & 63;
  const int frow = ln & 15, fgrp = ln >> 4;
  // stage K
  {
    const int srow = ln >> 3, schunk = ln & 7;
#pragma unroll
    for (int q = 0; q < 8; ++q) {
      int inst = w * 8 + q;
      int row = inst * 8 + srow;  // j
      const char* g = (const char*)(qkv + (size_t)(row * 8 + b) * 2304 + 768 + h * 64) +
                      ((schunk * 16) ^ ((row & 7) << 4));
      gload_lds16(g, Ks + inst * 1024);
    }
    // stage V^T (rows d, 512B)
#pragma unroll
    for (int q = 0; q < 8; ++q) {
      int inst = w * 8 + q;
      int row = inst * 2 + (ln >> 5);
      int cb = (ln & 31) * 16;
      const char* g = (const char*)(vT + (size_t)((b * Hn + h) * 64 + row) * 256) +
                      (cb ^ ((row & 7) << 4));
      gload_lds16(g, Vs + inst * 1024);
    }
  }
  // Q fragments from global
  bf16x8 qf[2];
  {
    int qrow = i0 + w * 16 + frow;
    const ushort* qg = qkv + (size_t)(qrow * 8 + b) * 2304 + h * 64 + fgrp * 8;
    qf[0] = *(const bf16x8*)qg;
    qf[1] = *(const bf16x8*)(qg + 32);
  }
  __syncthreads();
  // QK^T
  f32x4 s[16];
#pragma unroll
  for (int jtl = 0; jtl < 16; ++jtl) {
    int row = jtl * 16 + frow;
    const char* kb = Ks + row * 128;
    bf16x8 k0 = *(const bf16x8*)(kb + ((fgrp * 16) ^ ((row & 7) << 4)));
    bf16x8 k1 = *(const bf16x8*)(kb + ((64 + fgrp * 16) ^ ((row & 7) << 4)));
    f32x4 t = {};
    t = MFMA16(qf[0], k0, t);
    t = MFMA16(qf[1], k1, t);
    s[jtl] = t;
  }
  // bias + scale + softmax (rows fgrp*4+r, cols frow+16*jtl)
  float inv[4];
#pragma unroll
  for (int r = 0; r < 4; ++r) {
    int i = i0 + w * 16 + fgrp * 4 + r;
    const ushort* brow = biasb + (((size_t)b * Hn + h) * Nn + i) * Nn;
    float m = -3.0e38f;
#pragma unroll
    for (int jtl = 0; jtl < 16; ++jtl) {
      float v = s[jtl][r] * SCALE + bf2f(brow[jtl * 16 + frow]);
      s[jtl][r] = v;
      m = fmaxf(m, v);
    }
    m = fmaxf(m, __shfl_xor(m, 1)); m = fmaxf(m, __shfl_xor(m, 2));
    m = fmaxf(m, __shfl_xor(m, 4)); m = fmaxf(m, __shfl_xor(m, 8));
    float su = 0.f;
#pragma unroll
    for (int jtl = 0; jtl < 16; ++jtl) {
      float p = expf(s[jtl][r] - m);
      s[jtl][r] = p;
      su += p;
    }
    su += __shfl_xor(su, 1); su += __shfl_xor(su, 2);
    su += __shfl_xor(su, 4); su += __shfl_xor(su, 8);
    inv[r] = 1.0f / su;
  }
  __syncthreads();  // all waves done reading Ks
  // write P (unnormalized) into Ks region, per-wave [16][256] bf16 swizzled
  char* Ps = Ks + w * 8192;
#pragma unroll
  for (int r = 0; r < 4; ++r) {
    int prow = fgrp * 4 + r;
#pragma unroll
    for (int jtl = 0; jtl < 16; ++jtl) {
      int cb = jtl * 32 + frow * 2;
      *(ushort*)(Ps + prow * 512 + (cb ^ ((prow & 7) << 4))) = f2bf(s[jtl][r]);
    }
  }
  __syncthreads();
  // PV
  bf16x8 pf[8];
#pragma unroll
  for (int ks = 0; ks < 8; ++ks)
    pf[ks] = *(const bf16x8*)(Ps + frow * 512 + ((ks * 64 + fgrp * 16) ^ ((frow & 7) << 4)));
  f32x4 o[4] = {};
#pragma unroll
  for (int dt = 0; dt < 4; ++dt) {
#pragma unroll
    for (int ks = 0; ks < 8; ++ks) {
      int row = dt * 16 + frow;
      bf16x8 vf = *(const bf16x8*)(Vs + row * 512 + ((ks * 64 + fgrp * 16) ^ ((row & 7) << 4)));
      o[dt] = MFMA16(pf[ks], vf, o[dt]);
    }
  }
#pragma unroll
  for (int dt = 0; dt < 4; ++dt)
#pragma unroll
    for (int r = 0; r < 4; ++r) {
      int i = i0 + w * 16 + fgrp * 4 + r;
      Oout[(size_t)(i * 8 + b) * Dn + h * 64 + dt * 16 + frow] = f2bf(o[dt][r] * inv[r]);
    }
}

// ---------------- LayerNorm over D=768 ---------------------------------------
// MODE 0: bf16 out [T][D]; MODE 1: f32 out transposed to [B,N,D]
template <int MODE>
__global__ __launch_bounds__(256) void ln_kernel(
    const float* __restrict__ x, const float* __restrict__ sc,
    const float* __restrict__ bi, void* __restrict__ out) {
  int t = blockIdx.x;
  int tid = threadIdx.x;
  const float* xr = x + (size_t)t * Dn;
  float v0 = xr[tid], v1 = xr[tid + 256], v2 = xr[tid + 512];
  __shared__ float red[4], red2[4];
  float s = wave_sum(v0 + v1 + v2);
  if ((tid & 63) == 0) red[tid >> 6] = s;
  __syncthreads();
  float mean = (red[0] + red[1] + red[2] + red[3]) * (1.0f / 768.0f);
  float d0 = v0 - mean, d1 = v1 - mean, d2 = v2 - mean;
  float vs = wave_sum(d0 * d0 + d1 * d1 + d2 * d2);
  if ((tid & 63) == 0) red2[tid >> 6] = vs;
  __syncthreads();
  float var = (red2[0] + red2[1] + red2[2] + red2[3]) * (1.0f / 768.0f);
  float r = rsqrtf(var + 1e-5f);
  if (MODE == 0) {
    ushort* o = (ushort*)out + (size_t)t * Dn;
    o[tid]       = f2bf(d0 * r * sc[tid]       + bi[tid]);
    o[tid + 256] = f2bf(d1 * r * sc[tid + 256] + bi[tid + 256]);
    o[tid + 512] = f2bf(d2 * r * sc[tid + 512] + bi[tid + 512]);
  } else {
    int n = t >> 3, bb = t & 7;
    float* o = (float*)out + (size_t)(bb * Nn + n) * Dn;
    o[tid]       = d0 * r * sc[tid]       + bi[tid];
    o[tid + 256] = d1 * r * sc[tid + 256] + bi[tid + 256];
    o[tid + 512] = d2 * r * sc[tid + 512] + bi[tid + 512];
  }
}

// =============================================================================
extern "C" void kernel_launch(void* const* d_in, const int* in_sizes, int n_in,
                              void* d_out, int out_size, void* d_ws, size_t ws_size,
                              hipStream_t stream) {
  (void)in_sizes; (void)n_in; (void)out_size; (void)ws_size;
  const int*   atoms    = (const int*)  d_in[0];
  const float* pos      = (const float*)d_in[1];
  const float* atom_emb = (const float*)d_in[2];
  const float* gbf_means= (const float*)d_in[3];
  const float* gbf_stds = (const float*)d_in[4];
  const float* gbf_mul  = (const float*)d_in[5];
  const float* gbf_bias = (const float*)d_in[6];
  const float* bp_w1    = (const float*)d_in[7];
  const float* bp_b1    = (const float*)d_in[8];
  const float* bp_w2    = (const float*)d_in[9];
  const float* bp_b2    = (const float*)d_in[10];
  const float* edge_w   = (const float*)d_in[11];
  const float* edge_b   = (const float*)d_in[12];
  const float* ap_w     = (const float*)d_in[13];
  const float* ap_b     = (const float*)d_in[14];
  const float* ln1_s    = (const float*)d_in[15];
  const float* ln1_b    = (const float*)d_in[16];
  const float* wi       = (const float*)d_in[17];
  const float* bi       = (const float*)d_in[18];
  const float* wo       = (const float*)d_in[19];
  const float* bo       = (const float*)d_in[20];
  const float* ln2_s    = (const float*)d_in[21];
  const float* ln2_b    = (const float*)d_in[22];
  const float* w1       = (const float*)d_in[23];
  const float* b1       = (const float*)d_in[24];
  const float* w2       = (const float*)d_in[25];
  const float* b2       = (const float*)d_in[26];
  const float* fln_s    = (const float*)d_in[27];
  const float* fln_b    = (const float*)d_in[28];
  float* out = (float*)d_out;

  // workspace layout (u16 units unless noted)
  ushort* wsb   = (ushort*)d_ws;
  ushort* biasb = wsb;                                  // 6291456
  ushort* qkvb  = biasb + (size_t)Bn * Hn * Nn * Nn;    // 4718592 (also ffn mid, also apT)
  ushort* hb    = qkvb + (size_t)Tn * 2304;             // 1572864
  ushort* vT    = hb + (size_t)Tn * Dn;                 // 1572864 (efb overlays start)
  ushort* wiT   = vT + (size_t)Bn * Hn * 64 * 256;      // 7077888
  ushort* woT   = wiT + (size_t)4 * 2304 * Dn;          // 2359296
  ushort* w1T   = woT + (size_t)4 * Dn * Dn;            // 2359296
  ushort* w2T   = w1T + (size_t)4 * Dn * Dn;            // 2359296
  ushort* w1bT  = w2T + (size_t)4 * Dn * Dn;            // 16384
  float*  xbuf  = (float*)(w1bT + 16384);               // Tn*Dn f32
  ushort* apT   = qkvb;                                 // overlay (dead before qkv GEMM)
  ushort* ffnb  = qkvb;                                 // overlay (qkv dead in FFN phase)
  float*  efb   = (float*)vT;                           // overlay (dead before layer 0)

  // weight prep
  wtrans<<<dim3(12, 12, 1), 256, 0, stream>>>(ap_w, apT, 768, 768);
  wtrans<<<dim3(36, 12, 4), 256, 0, stream>>>(wi, wiT, 768, 2304);
  wtrans<<<dim3(12, 12, 4), 256, 0, stream>>>(wo, woT, 768, 768);
  wtrans<<<dim3(12, 12, 4), 256, 0, stream>>>(w1, w1T, 768, 768);
  wtrans<<<dim3(12, 12, 4), 256, 0, stream>>>(w2, w2T, 768, 768);
  wtrans<<<dim3(2, 2, 1), 256, 0, stream>>>(bp_w1, w1bT, 128, 128);

  dim3 gridNB(Nn, Bn);
  ef_kernel<<<gridNB, 128, 0, stream>>>(atoms, pos, gbf_means, gbf_stds, gbf_mul, gbf_bias, efb);
  gbias_kernel<<<dim3(4, Nn, Bn), 256, 0, stream>>>(atoms, pos, gbf_means, gbf_stds,
                                                    gbf_mul, gbf_bias, w1bT, bp_b1, bp_w2, bp_b2, biasb);
  node_kernel<<<gridNB, 256, 0, stream>>>(atoms, efb, atom_emb, edge_w, edge_b, hb);
  mgemm<3><<<dim3(12, 32), 256, 0, stream>>>(hb, apT, ap_b, nullptr, xbuf, Tn, Dn, Dn);

  for (int it = 0; it < 8; ++it) {
    int l = it & 3;
    ln_kernel<0><<<Tn, 256, 0, stream>>>(xbuf, ln1_s + l * Dn, ln1_b + l * Dn, hb);
    mgemm<0><<<dim3(36, 32), 256, 0, stream>>>(hb, wiT + (size_t)l * 2304 * Dn,
                                               bi + l * 2304, nullptr, qkvb, Tn, Dn, 2304);
    vtrans<<<dim3(Hn, Bn), 256, 0, stream>>>(qkvb, vT);
    attn_mfma<<<dim3(4, Hn, Bn), 256, 0, stream>>>(qkvb, vT, biasb, hb);
    mgemm<2><<<dim3(12, 32), 256, 0, stream>>>(hb, woT + (size_t)l * Dn * Dn,
                                               bo + l * Dn, xbuf, xbuf, Tn, Dn, Dn);
    ln_kernel<0><<<Tn, 256, 0, stream>>>(xbuf, ln2_s + l * Dn, ln2_b + l * Dn, hb);
    mgemm<1><<<dim3(12, 32), 256, 0, stream>>>(hb, w1T + (size_t)l * Dn * Dn,
                                               b1 + l * Dn, nullptr, ffnb, Tn, Dn, Dn);
    mgemm<2><<<dim3(12, 32), 256, 0, stream>>>(ffnb, w2T + (size_t)l * Dn * Dn,
                                               b2 + l * Dn, xbuf, xbuf, Tn, Dn, Dn);
  }
  ln_kernel<1><<<Tn, 256, 0, stream>>>(xbuf, fln_s, fln_b, out);
}

// Round 3
// 924.122 us; speedup vs baseline: 12.3465x; 1.0357x over previous
//
#include <hip/hip_runtime.h>
#include <math.h>

constexpr int Bn = 8, Nn = 256, Dn = 768, Hn = 12, Kn = 128;
constexpr int Tn = Nn * Bn;      // 2048 tokens
constexpr float SCALE = 0.125f;  // HD^-0.5, HD=64
constexpr float NEGB = -1e9f;

typedef __attribute__((ext_vector_type(8))) short bf16x8;
typedef __attribute__((ext_vector_type(4))) float f32x4;

#define MFMA16(a, b, c) __builtin_amdgcn_mfma_f32_16x16x32_bf16((a), (b), (c), 0, 0, 0)

__device__ __forceinline__ void gload_lds16(const void* g, void* l) {
  __builtin_amdgcn_global_load_lds(
      (const __attribute__((address_space(1))) void*)g,
      (__attribute__((address_space(3))) void*)l, 16, 0, 0);
}

__device__ __forceinline__ ushort f2bf(float x) {
  union { float f; unsigned u; } v; v.f = x;
  unsigned r = (v.u + 0x7fff + ((v.u >> 16) & 1)) >> 16;
  return (ushort)r;
}
__device__ __forceinline__ float bf2f(ushort u) {
  union { unsigned u; float f; } v; v.u = ((unsigned)u) << 16;
  return v.f;
}
__device__ __forceinline__ float gelu_f(float x) {
  return 0.5f * x * (1.0f + erff(x * 0.70710678118654752f));
}
// tanh-approx gelu (|err| <~3e-3, used only in the bias MLP path)
__device__ __forceinline__ float gelu_fast(float x) {
  float u = x * (0.7978845608f + 0.0356774081f * x * x);
  float e = __expf(2.0f * u);
  float t = 1.0f - 2.0f / (e + 1.0f);
  return 0.5f * x * (1.0f + t);
}
__device__ __forceinline__ float wave_sum(float v) {
#pragma unroll
  for (int off = 32; off; off >>= 1) v += __shfl_xor(v, off);
  return v;
}

// ---------------- weight transpose+convert: W[K,N] f32 -> WT[N,K] bf16 -------
__global__ __launch_bounds__(256) void wtrans(const float* __restrict__ W,
                                              ushort* __restrict__ WT,
                                              int Kd, int Nd) {
  __shared__ float tile[64][65];
  const float* Wl = W + (size_t)blockIdx.z * Kd * Nd;
  ushort* WTl = WT + (size_t)blockIdx.z * Kd * Nd;
  int n0 = blockIdx.x * 64, k0 = blockIdx.y * 64;
  int tid = threadIdx.x;
  for (int e = tid; e < 64 * 64; e += 256) {
    int r = e >> 6, c = e & 63;
    tile[r][c] = Wl[(size_t)(k0 + r) * Nd + n0 + c];
  }
  __syncthreads();
  for (int e = tid; e < 64 * 64; e += 256) {
    int r = e >> 6, c = e & 63;
    WTl[(size_t)(n0 + r) * Kd + k0 + c] = f2bf(tile[c][r]);
  }
}

// ---------------- Gaussian edge features: ef[b,i,k] = sum_j (!pad_j) gauss ----
__global__ __launch_bounds__(128) void ef_kernel(
    const int* __restrict__ atoms, const float* __restrict__ pos,
    const float* __restrict__ means, const float* __restrict__ stds,
    const float* __restrict__ gmul, const float* __restrict__ gbias,
    float* __restrict__ ef) {
  int i = blockIdx.x, b = blockIdx.y;
  __shared__ float dist[Nn], ml[Nn], bs2[Nn];
  __shared__ int padm[Nn];
  int tid = threadIdx.x;
  int ai = atoms[b * Nn + i];
  float px = pos[(b * Nn + i) * 3], py = pos[(b * Nn + i) * 3 + 1], pz = pos[(b * Nn + i) * 3 + 2];
  for (int j = tid; j < Nn; j += 128) {
    int aj = atoms[b * Nn + j];
    float dx = px - pos[(b * Nn + j) * 3];
    float dy = py - pos[(b * Nn + j) * 3 + 1];
    float dz = pz - pos[(b * Nn + j) * 3 + 2];
    float sq = dx * dx + dy * dy + dz * dz;
    dist[j] = sq > 0.f ? sqrtf(sq) : 0.f;
    int et = ai * 10 + aj;
    ml[j] = gmul[et];
    bs2[j] = gbias[et];
    padm[j] = (aj == 0);
  }
  __syncthreads();
  int k = tid;
  float mean = means[k];
  float sd = fabsf(stds[k]) + 1e-5f;
  float inv = 1.0f / sd;
  float cn = 1.0f / (sqrtf(2.0f * 3.14159f) * sd);
  float acc = 0.f;
  for (int j = 0; j < Nn; ++j) {
    if (padm[j]) continue;
    float t = (ml[j] * dist[j] + bs2[j] - mean) * inv;
    acc += __expf(-0.5f * t * t);
  }
  ef[(b * Nn + i) * Kn + k] = acc * cn;
}

// ---------------- bias MLP via MFMA: one block per (b,i), 4 j-tiles ----------
__global__ __launch_bounds__(256) void gbias_kernel(
    const int* __restrict__ atoms, const float* __restrict__ pos,
    const float* __restrict__ means, const float* __restrict__ stds,
    const float* __restrict__ gmul, const float* __restrict__ gbias_,
    const ushort* __restrict__ w1T, const float* __restrict__ b1,
    const float* __restrict__ w2, const float* __restrict__ b2,
    ushort* __restrict__ biasb) {
  int i = blockIdx.x, b = blockIdx.y;
  __shared__ char W1s[32768];      // [128 n][128 k] bf16, XOR-swizzled; persists
  __shared__ char Ag[16384];       // phase B: gbf [64 j][128 k] swz / phase C: gT [128 n][64 j] swz
  __shared__ float W2s[128 * 12];
  __shared__ float b1s[128], mns[128], sdsi[128], cns[128];
  __shared__ float dls[256], mll[256], bsl[256];
  __shared__ int pml[256];
  const int tid = threadIdx.x, w = tid >> 6, ln = tid & 63;
  const int frow = ln & 15, fgrp = ln >> 4;
  // stage W1T once (pre-swizzled source -> linear LDS; read side applies swizzle)
  {
    int srow = ln >> 4, sc = ln & 15;
#pragma unroll
    for (int q = 0; q < 8; ++q) {
      int inst = w * 8 + q;
      int row = inst * 4 + srow;
      const char* g = (const char*)(w1T + row * 128) + ((sc * 16) ^ ((row & 7) << 4));
      gload_lds16(g, W1s + inst * 1024);
    }
  }
  if (tid < 128) {
    mns[tid] = means[tid];
    float sd = fabsf(stds[tid]) + 1e-5f;
    sdsi[tid] = 1.0f / sd;
    cns[tid] = 1.0f / (sqrtf(2.0f * 3.14159f) * sd);
    b1s[tid] = b1[tid];
  }
  for (int e = tid; e < 128 * 12; e += 256) W2s[e] = w2[e];
  {
    int ai = atoms[b * Nn + i];
    int j = tid;
    int aj = atoms[b * Nn + j];
    float dx = pos[(b * Nn + i) * 3]     - pos[(b * Nn + j) * 3];
    float dy = pos[(b * Nn + i) * 3 + 1] - pos[(b * Nn + j) * 3 + 1];
    float dz = pos[(b * Nn + i) * 3 + 2] - pos[(b * Nn + j) * 3 + 2];
    float sq = dx * dx + dy * dy + dz * dz;
    dls[j] = sq > 0.f ? sqrtf(sq) : 0.f;
    int et = ai * 10 + aj;
    mll[j] = gmul[et];
    bsl[j] = gbias_[et];
    pml[j] = (aj == 0);
  }
  __syncthreads();

  for (int jt = 0; jt < 4; ++jt) {
    int j0 = jt * 64;
    // build Ag: gbf tile [64][128] bf16 swizzled
    for (int idx = tid; idx < 64 * 128; idx += 256) {
      int row = idx >> 7, k = idx & 127;
      int jj = j0 + row;
      float t = (mll[jj] * dls[jj] + bsl[jj] - mns[k]) * sdsi[k];
      float g = __expf(-0.5f * t * t) * cns[k];
      *(ushort*)(Ag + row * 256 + ((2 * k) ^ ((row & 7) << 4))) = f2bf(g);
    }
    __syncthreads();
    // phase B: [64,128]@[128,128] via MFMA; wave w owns j-rows w*16..+16
    f32x4 acc[8] = {};
    const int arow = w * 16 + frow;
#pragma unroll
    for (int ks = 0; ks < 4; ++ks) {
      bf16x8 af = *(const bf16x8*)(Ag + arow * 256 + ((ks * 64 + fgrp * 16) ^ ((arow & 7) << 4)));
#pragma unroll
      for (int nt = 0; nt < 8; ++nt) {
        int brow = nt * 16 + frow;
        bf16x8 bfv = *(const bf16x8*)(W1s + brow * 256 + ((ks * 64 + fgrp * 16) ^ ((brow & 7) << 4)));
        acc[nt] = MFMA16(af, bfv, acc[nt]);
      }
    }
    __syncthreads();  // Ag reads done; reuse as gT
    // gelu + store transposed gT[n][j] bf16 swizzled
#pragma unroll
    for (int nt = 0; nt < 8; ++nt) {
      int n = nt * 16 + frow;
#pragma unroll
      for (int r = 0; r < 4; ++r) {
        int jloc = w * 16 + fgrp * 4 + r;
        float g = gelu_fast(acc[nt][r] + b1s[n]);
        *(ushort*)(Ag + n * 128 + ((2 * jloc) ^ ((n & 7) << 4))) = f2bf(g);
      }
    }
    __syncthreads();
    // phase C: out[j,h] = sum_n gT[n][j] * W2[n,h]; thread -> (j = tid&63, 3 h's)
    {
      int jl = tid & 63, hb = (tid >> 6) * 3;
      float a0 = 0.f, a1 = 0.f, a2 = 0.f;
#pragma unroll 8
      for (int k = 0; k < 128; ++k) {
        float g = bf2f(*(const ushort*)(Ag + k * 128 + ((2 * jl) ^ ((k & 7) << 4))));
        a0 += g * W2s[k * 12 + hb];
        a1 += g * W2s[k * 12 + hb + 1];
        a2 += g * W2s[k * 12 + hb + 2];
      }
      int jg = j0 + jl;
      int padj = pml[jg];
      float r0 = padj ? NEGB : (a0 + b2[hb]);
      float r1 = padj ? NEGB : (a1 + b2[hb + 1]);
      float r2 = padj ? NEGB : (a2 + b2[hb + 2]);
      biasb[(((size_t)b * Hn + hb) * Nn + i) * Nn + jg] = f2bf(r0);
      biasb[(((size_t)b * Hn + hb + 1) * Nn + i) * Nn + jg] = f2bf(r1);
      biasb[(((size_t)b * Hn + hb + 2) * Nn + i) * Nn + jg] = f2bf(r2);
    }
    __syncthreads();  // before next jt overwrites Ag
  }
}

// ---------------- node = emb[atoms] + ef@edge_w + edge_b -> [N,B,D] bf16 ------
__global__ __launch_bounds__(256) void node_kernel(
    const int* __restrict__ atoms, const float* __restrict__ ef,
    const float* __restrict__ emb, const float* __restrict__ ew,
    const float* __restrict__ eb, ushort* __restrict__ nodeT) {
  int n = blockIdx.x, b = blockIdx.y;
  __shared__ float efs[Kn];
  int tid = threadIdx.x;
  if (tid < Kn) efs[tid] = ef[(b * Nn + n) * Kn + tid];
  __syncthreads();
  int a = atoms[b * Nn + n];
  for (int d = tid; d < Dn; d += 256) {
    float acc = emb[a * Dn + d] + eb[d];
#pragma unroll 8
    for (int k = 0; k < Kn; ++k) acc += efs[k] * ew[k * Dn + d];
    nodeT[(size_t)(n * Bn + b) * Dn + d] = f2bf(acc);
  }
}

// ---------------- MFMA GEMM 64x64 tile (for N=768 GEMMs) --------------------
// MODE 0: bf16 out; 1: gelu bf16 out; 2: f32 out + residual; 3: f32 out
template <int MODE>
__global__ __launch_bounds__(256, 4) void mgemm(
    const ushort* __restrict__ A, const ushort* __restrict__ WT,
    const float* __restrict__ bias, const float* __restrict__ res,
    void* __restrict__ Cout, int M, int Kd, int Nd) {
  __shared__ char smem[16384];
  char* ldsA = smem;
  char* ldsB = smem + 8192;
  const int tid = threadIdx.x, w = tid >> 6, ln = tid & 63;
  const int m0 = blockIdx.y * 64, n0 = blockIdx.x * 64;
  const int wm = (w >> 1) * 32, wn = (w & 1) * 32;
  const int srow = ln >> 3, schunk = ln & 7;
  const int sswz = (schunk * 16) ^ (srow << 4);
  const int frow = ln & 15, fgrp = ln >> 4;
  f32x4 acc[2][2] = {};
  for (int kt = 0; kt < Kd; kt += 64) {
    __syncthreads();
#pragma unroll
    for (int q = 0; q < 2; ++q) {
      int r = (w * 2 + q) * 8 + srow;
      gload_lds16((const char*)(A + (size_t)(m0 + r) * Kd + kt) + sswz, ldsA + (w * 2 + q) * 1024);
    }
#pragma unroll
    for (int q = 0; q < 2; ++q) {
      int r = (w * 2 + q) * 8 + srow;
      gload_lds16((const char*)(WT + (size_t)(n0 + r) * Kd + kt) + sswz, ldsB + (w * 2 + q) * 1024);
    }
    __syncthreads();
#pragma unroll
    for (int ks = 0; ks < 2; ++ks) {
      bf16x8 af[2], bfv[2];
#pragma unroll
      for (int mt = 0; mt < 2; ++mt) {
        int row = wm + mt * 16 + frow;
        af[mt] = *(const bf16x8*)(ldsA + row * 128 + ((ks * 64 + fgrp * 16) ^ ((row & 7) << 4)));
      }
#pragma unroll
      for (int nt = 0; nt < 2; ++nt) {
        int row = wn + nt * 16 + frow;
        bfv[nt] = *(const bf16x8*)(ldsB + row * 128 + ((ks * 64 + fgrp * 16) ^ ((row & 7) << 4)));
      }
      acc[0][0] = MFMA16(af[0], bfv[0], acc[0][0]);
      acc[0][1] = MFMA16(af[0], bfv[1], acc[0][1]);
      acc[1][0] = MFMA16(af[1], bfv[0], acc[1][0]);
      acc[1][1] = MFMA16(af[1], bfv[1], acc[1][1]);
    }
  }
#pragma unroll
  for (int nt = 0; nt < 2; ++nt) {
    int n = n0 + wn + nt * 16 + frow;
    float bv = bias[n];
#pragma unroll
    for (int mt = 0; mt < 2; ++mt) {
#pragma unroll
      for (int r = 0; r < 4; ++r) {
        int m = m0 + wm + mt * 16 + fgrp * 4 + r;
        float v = acc[mt][nt][r] + bv;
        if (MODE == 1) v = gelu_f(v);
        if (MODE == 2) v += res[(size_t)m * Nd + n];
        if (MODE <= 1) ((ushort*)Cout)[(size_t)m * Nd + n] = f2bf(v);
        else           ((float*)Cout)[(size_t)m * Nd + n] = v;
      }
    }
  }
}

// ---------------- MFMA GEMM 128x128 tile (qkv GEMM) -------------------------
template <int MODE>
__global__ __launch_bounds__(256, 2) void mgemm128(
    const ushort* __restrict__ A, const ushort* __restrict__ WT,
    const float* __restrict__ bias, const float* __restrict__ res,
    void* __restrict__ Cout, int M, int Kd, int Nd) {
  __shared__ char smem[32768];
  char* ldsA = smem;
  char* ldsB = smem + 16384;
  const int tid = threadIdx.x, w = tid >> 6, ln = tid & 63;
  const int m0 = blockIdx.y * 128, n0 = blockIdx.x * 128;
  const int wm = (w >> 1) * 64, wn = (w & 1) * 64;
  const int srow = ln >> 3, schunk = ln & 7;
  const int sswz = (schunk * 16) ^ (srow << 4);
  const int frow = ln & 15, fgrp = ln >> 4;
  f32x4 acc[4][4] = {};
  for (int kt = 0; kt < Kd; kt += 64) {
    __syncthreads();
#pragma unroll
    for (int q = 0; q < 4; ++q) {
      int r = (w * 4 + q) * 8 + srow;
      gload_lds16((const char*)(A + (size_t)(m0 + r) * Kd + kt) + sswz, ldsA + (w * 4 + q) * 1024);
    }
#pragma unroll
    for (int q = 0; q < 4; ++q) {
      int r = (w * 4 + q) * 8 + srow;
      gload_lds16((const char*)(WT + (size_t)(n0 + r) * Kd + kt) + sswz, ldsB + (w * 4 + q) * 1024);
    }
    __syncthreads();
#pragma unroll
    for (int ks = 0; ks < 2; ++ks) {
      bf16x8 af[4], bfv[4];
#pragma unroll
      for (int mt = 0; mt < 4; ++mt) {
        int row = wm + mt * 16 + frow;
        af[mt] = *(const bf16x8*)(ldsA + row * 128 + ((ks * 64 + fgrp * 16) ^ ((row & 7) << 4)));
      }
#pragma unroll
      for (int nt = 0; nt < 4; ++nt) {
        int row = wn + nt * 16 + frow;
        bfv[nt] = *(const bf16x8*)(ldsB + row * 128 + ((ks * 64 + fgrp * 16) ^ ((row & 7) << 4)));
      }
#pragma unroll
      for (int mt = 0; mt < 4; ++mt)
#pragma unroll
        for (int nt = 0; nt < 4; ++nt)
          acc[mt][nt] = MFMA16(af[mt], bfv[nt], acc[mt][nt]);
    }
  }
#pragma unroll
  for (int nt = 0; nt < 4; ++nt) {
    int n = n0 + wn + nt * 16 + frow;
    float bv = bias[n];
#pragma unroll
    for (int mt = 0; mt < 4; ++mt) {
#pragma unroll
      for (int r = 0; r < 4; ++r) {
        int m = m0 + wm + mt * 16 + fgrp * 4 + r;
        float v = acc[mt][nt][r] + bv;
        if (MODE == 1) v = gelu_f(v);
        if (MODE == 2) v += res[(size_t)m * Nd + n];
        if (MODE <= 1) ((ushort*)Cout)[(size_t)m * Nd + n] = f2bf(v);
        else           ((float*)Cout)[(size_t)m * Nd + n] = v;
      }
    }
  }
}

// ---------------- per-layer V transpose: qkv V section -> vT[b,h,d,j] bf16 ----
__global__ __launch_bounds__(256) void vtrans(const ushort* __restrict__ qkvb,
                                              ushort* __restrict__ vT) {
  int h = blockIdx.x, b = blockIdx.y;
  __shared__ ushort Vs[256][64];
  int tid = threadIdx.x;
  for (int idx = tid; idx < 2048; idx += 256) {
    int j = idx >> 3, ch = idx & 7;
    *(bf16x8*)&Vs[j][ch * 8] =
        *(const bf16x8*)(qkvb + (size_t)(j * 8 + b) * 2304 + 1536 + h * 64 + ch * 8);
  }
  __syncthreads();
  char* base = (char*)(vT + (size_t)((b * Hn + h) * 64) * 256);
  for (int idx = tid; idx < 2048; idx += 256) {
    int d = idx & 63, jc = idx >> 6;
    ushort tmp[8];
#pragma unroll
    for (int jj = 0; jj < 8; ++jj) tmp[jj] = Vs[jc * 8 + jj][d];
    *(bf16x8*)(base + d * 512 + jc * 16) = *(bf16x8*)tmp;
  }
}

// ---------------- MFMA attention: block = (b, h, 64 i-rows) -------------------
__global__ __launch_bounds__(256, 2) void attn_mfma(
    const ushort* __restrict__ qkv, const ushort* __restrict__ vT,
    const ushort* __restrict__ biasb, ushort* __restrict__ Oout) {
  int it = blockIdx.x, h = blockIdx.y, b = blockIdx.z;
  int i0 = it * 64;
  __shared__ char smem[65536];
  char* Ks = smem;           // [256 j][64 k] bf16 swizzled; later P[4][16][256]
  char* Vs = smem + 32768;   // [64 d][256 j] bf16 swizzled (V^T)
  const int tid = threadIdx.x, w = tid >> 6, ln = tid & 63;
  const int frow = ln & 15, fgrp = ln >> 4;
  // stage K
  {
    const int srow = ln >> 3, schunk = ln & 7;
#pragma unroll
    for (int q = 0; q < 8; ++q) {
      int inst = w * 8 + q;
      int row = inst * 8 + srow;  // j
      const char* g = (const char*)(qkv + (size_t)(row * 8 + b) * 2304 + 768 + h * 64) +
                      ((schunk * 16) ^ ((row & 7) << 4));
      gload_lds16(g, Ks + inst * 1024);
    }
    // stage V^T (rows d, 512B)
#pragma unroll
    for (int q = 0; q < 8; ++q) {
      int inst = w * 8 + q;
      int row = inst * 2 + (ln >> 5);
      int cb = (ln & 31) * 16;
      const char* g = (const char*)(vT + (size_t)((b * Hn + h) * 64 + row) * 256) +
                      (cb ^ ((row & 7) << 4));
      gload_lds16(g, Vs + inst * 1024);
    }
  }
  // Q fragments from global
  bf16x8 qf[2];
  {
    int qrow = i0 + w * 16 + frow;
    const ushort* qg = qkv + (size_t)(qrow * 8 + b) * 2304 + h * 64 + fgrp * 8;
    qf[0] = *(const bf16x8*)qg;
    qf[1] = *(const bf16x8*)(qg + 32);
  }
  __syncthreads();
  // QK^T
  f32x4 s[16];
#pragma unroll
  for (int jtl = 0; jtl < 16; ++jtl) {
    int row = jtl * 16 + frow;
    const char* kb = Ks + row * 128;
    bf16x8 k0 = *(const bf16x8*)(kb + ((fgrp * 16) ^ ((row & 7) << 4)));
    bf16x8 k1 = *(const bf16x8*)(kb + ((64 + fgrp * 16) ^ ((row & 7) << 4)));
    f32x4 t = {};
    t = MFMA16(qf[0], k0, t);
    t = MFMA16(qf[1], k1, t);
    s[jtl] = t;
  }
  // bias + scale + softmax (rows fgrp*4+r, cols frow+16*jtl)
  float inv[4];
#pragma unroll
  for (int r = 0; r < 4; ++r) {
    int i = i0 + w * 16 + fgrp * 4 + r;
    const ushort* brow = biasb + (((size_t)b * Hn + h) * Nn + i) * Nn;
    float m = -3.0e38f;
#pragma unroll
    for (int jtl = 0; jtl < 16; ++jtl) {
      float v = s[jtl][r] * SCALE + bf2f(brow[jtl * 16 + frow]);
      s[jtl][r] = v;
      m = fmaxf(m, v);
    }
    m = fmaxf(m, __shfl_xor(m, 1)); m = fmaxf(m, __shfl_xor(m, 2));
    m = fmaxf(m, __shfl_xor(m, 4)); m = fmaxf(m, __shfl_xor(m, 8));
    float su = 0.f;
#pragma unroll
    for (int jtl = 0; jtl < 16; ++jtl) {
      float p = __expf(s[jtl][r] - m);
      s[jtl][r] = p;
      su += p;
    }
    su += __shfl_xor(su, 1); su += __shfl_xor(su, 2);
    su += __shfl_xor(su, 4); su += __shfl_xor(su, 8);
    inv[r] = 1.0f / su;
  }
  __syncthreads();  // all waves done reading Ks
  // write P (unnormalized) into Ks region, per-wave [16][256] bf16 swizzled
  char* Ps = Ks + w * 8192;
#pragma unroll
  for (int r = 0; r < 4; ++r) {
    int prow = fgrp * 4 + r;
#pragma unroll
    for (int jtl = 0; jtl < 16; ++jtl) {
      int cb = jtl * 32 + frow * 2;
      *(ushort*)(Ps + prow * 512 + (cb ^ ((prow & 7) << 4))) = f2bf(s[jtl][r]);
    }
  }
  __syncthreads();
  // PV
  bf16x8 pf[8];
#pragma unroll
  for (int ks = 0; ks < 8; ++ks)
    pf[ks] = *(const bf16x8*)(Ps + frow * 512 + ((ks * 64 + fgrp * 16) ^ ((frow & 7) << 4)));
  f32x4 o[4] = {};
#pragma unroll
  for (int dt = 0; dt < 4; ++dt) {
#pragma unroll
    for (int ks = 0; ks < 8; ++ks) {
      int row = dt * 16 + frow;
      bf16x8 vf = *(const bf16x8*)(Vs + row * 512 + ((ks * 64 + fgrp * 16) ^ ((row & 7) << 4)));
      o[dt] = MFMA16(pf[ks], vf, o[dt]);
    }
  }
#pragma unroll
  for (int dt = 0; dt < 4; ++dt)
#pragma unroll
    for (int r = 0; r < 4; ++r) {
      int i = i0 + w * 16 + fgrp * 4 + r;
      Oout[(size_t)(i * 8 + b) * Dn + h * 64 + dt * 16 + frow] = f2bf(o[dt][r] * inv[r]);
    }
}

// ---------------- LayerNorm over D=768 ---------------------------------------
// MODE 0: bf16 out [T][D]; MODE 1: f32 out transposed to [B,N,D]
template <int MODE>
__global__ __launch_bounds__(256) void ln_kernel(
    const float* __restrict__ x, const float* __restrict__ sc,
    const float* __restrict__ bi, void* __restrict__ out) {
  int t = blockIdx.x;
  int tid = threadIdx.x;
  const float* xr = x + (size_t)t * Dn;
  float v0 = xr[tid], v1 = xr[tid + 256], v2 = xr[tid + 512];
  __shared__ float red[4], red2[4];
  float s = wave_sum(v0 + v1 + v2);
  if ((tid & 63) == 0) red[tid >> 6] = s;
  __syncthreads();
  float mean = (red[0] + red[1] + red[2] + red[3]) * (1.0f / 768.0f);
  float d0 = v0 - mean, d1 = v1 - mean, d2 = v2 - mean;
  float vs = wave_sum(d0 * d0 + d1 * d1 + d2 * d2);
  if ((tid & 63) == 0) red2[tid >> 6] = vs;
  __syncthreads();
  float var = (red2[0] + red2[1] + red2[2] + red2[3]) * (1.0f / 768.0f);
  float r = rsqrtf(var + 1e-5f);
  if (MODE == 0) {
    ushort* o = (ushort*)out + (size_t)t * Dn;
    o[tid]       = f2bf(d0 * r * sc[tid]       + bi[tid]);
    o[tid + 256] = f2bf(d1 * r * sc[tid + 256] + bi[tid + 256]);
    o[tid + 512] = f2bf(d2 * r * sc[tid + 512] + bi[tid + 512]);
  } else {
    int n = t >> 3, bb = t & 7;
    float* o = (float*)out + (size_t)(bb * Nn + n) * Dn;
    o[tid]       = d0 * r * sc[tid]       + bi[tid];
    o[tid + 256] = d1 * r * sc[tid + 256] + bi[tid + 256];
    o[tid + 512] = d2 * r * sc[tid + 512] + bi[tid + 512];
  }
}

// =============================================================================
extern "C" void kernel_launch(void* const* d_in, const int* in_sizes, int n_in,
                              void* d_out, int out_size, void* d_ws, size_t ws_size,
                              hipStream_t stream) {
  (void)in_sizes; (void)n_in; (void)out_size; (void)ws_size;
  const int*   atoms    = (const int*)  d_in[0];
  const float* pos      = (const float*)d_in[1];
  const float* atom_emb = (const float*)d_in[2];
  const float* gbf_means= (const float*)d_in[3];
  const float* gbf_stds = (const float*)d_in[4];
  const float* gbf_mul  = (const float*)d_in[5];
  const float* gbf_bias = (const float*)d_in[6];
  const float* bp_w1    = (const float*)d_in[7];
  const float* bp_b1    = (const float*)d_in[8];
  const float* bp_w2    = (const float*)d_in[9];
  const float* bp_b2    = (const float*)d_in[10];
  const float* edge_w   = (const float*)d_in[11];
  const float* edge_b   = (const float*)d_in[12];
  const float* ap_w     = (const float*)d_in[13];
  const float* ap_b     = (const float*)d_in[14];
  const float* ln1_s    = (const float*)d_in[15];
  const float* ln1_b    = (const float*)d_in[16];
  const float* wi       = (const float*)d_in[17];
  const float* bi       = (const float*)d_in[18];
  const float* wo       = (const float*)d_in[19];
  const float* bo       = (const float*)d_in[20];
  const float* ln2_s    = (const float*)d_in[21];
  const float* ln2_b    = (const float*)d_in[22];
  const float* w1       = (const float*)d_in[23];
  const float* b1       = (const float*)d_in[24];
  const float* w2       = (const float*)d_in[25];
  const float* b2       = (const float*)d_in[26];
  const float* fln_s    = (const float*)d_in[27];
  const float* fln_b    = (const float*)d_in[28];
  float* out = (float*)d_out;

  // workspace layout (u16 units unless noted)
  ushort* wsb   = (ushort*)d_ws;
  ushort* biasb = wsb;                                  // 6291456
  ushort* qkvb  = biasb + (size_t)Bn * Hn * Nn * Nn;    // 4718592 (also ffn mid, also apT)
  ushort* hb    = qkvb + (size_t)Tn * 2304;             // 1572864
  ushort* vT    = hb + (size_t)Tn * Dn;                 // 1572864 (efb overlays start)
  ushort* wiT   = vT + (size_t)Bn * Hn * 64 * 256;      // 7077888
  ushort* woT   = wiT + (size_t)4 * 2304 * Dn;          // 2359296
  ushort* w1T   = woT + (size_t)4 * Dn * Dn;            // 2359296
  ushort* w2T   = w1T + (size_t)4 * Dn * Dn;            // 2359296
  ushort* w1bT  = w2T + (size_t)4 * Dn * Dn;            // 16384
  float*  xbuf  = (float*)(w1bT + 16384);               // Tn*Dn f32
  ushort* apT   = qkvb;                                 // overlay (dead before qkv GEMM)
  ushort* ffnb  = qkvb;                                 // overlay (qkv dead in FFN phase)
  float*  efb   = (float*)vT;                           // overlay (dead before layer 0)

  // weight prep
  wtrans<<<dim3(12, 12, 1), 256, 0, stream>>>(ap_w, apT, 768, 768);
  wtrans<<<dim3(36, 12, 4), 256, 0, stream>>>(wi, wiT, 768, 2304);
  wtrans<<<dim3(12, 12, 4), 256, 0, stream>>>(wo, woT, 768, 768);
  wtrans<<<dim3(12, 12, 4), 256, 0, stream>>>(w1, w1T, 768, 768);
  wtrans<<<dim3(12, 12, 4), 256, 0, stream>>>(w2, w2T, 768, 768);
  wtrans<<<dim3(2, 2, 1), 256, 0, stream>>>(bp_w1, w1bT, 128, 128);

  dim3 gridNB(Nn, Bn);
  ef_kernel<<<gridNB, 128, 0, stream>>>(atoms, pos, gbf_means, gbf_stds, gbf_mul, gbf_bias, efb);
  gbias_kernel<<<gridNB, 256, 0, stream>>>(atoms, pos, gbf_means, gbf_stds,
                                           gbf_mul, gbf_bias, w1bT, bp_b1, bp_w2, bp_b2, biasb);
  node_kernel<<<gridNB, 256, 0, stream>>>(atoms, efb, atom_emb, edge_w, edge_b, hb);
  mgemm<3><<<dim3(12, 32), 256, 0, stream>>>(hb, apT, ap_b, nullptr, xbuf, Tn, Dn, Dn);

  for (int it = 0; it < 8; ++it) {
    int l = it & 3;
    ln_kernel<0><<<Tn, 256, 0, stream>>>(xbuf, ln1_s + l * Dn, ln1_b + l * Dn, hb);
    mgemm128<0><<<dim3(18, 16), 256, 0, stream>>>(hb, wiT + (size_t)l * 2304 * Dn,
                                                  bi + l * 2304, nullptr, qkvb, Tn, Dn, 2304);
    vtrans<<<dim3(Hn, Bn), 256, 0, stream>>>(qkvb, vT);
    attn_mfma<<<dim3(4, Hn, Bn), 256, 0, stream>>>(qkvb, vT, biasb, hb);
    mgemm<2><<<dim3(12, 32), 256, 0, stream>>>(hb, woT + (size_t)l * Dn * Dn,
                                               bo + l * Dn, xbuf, xbuf, Tn, Dn, Dn);
    ln_kernel<0><<<Tn, 256, 0, stream>>>(xbuf, ln2_s + l * Dn, ln2_b + l * Dn, hb);
    mgemm<1><<<dim3(12, 32), 256, 0, stream>>>(hb, w1T + (size_t)l * Dn * Dn,
                                               b1 + l * Dn, nullptr, ffnb, Tn, Dn, Dn);
    mgemm<2><<<dim3(12, 32), 256, 0, stream>>>(ffnb, w2T + (size_t)l * Dn * Dn,
                                               b2 + l * Dn, xbuf, xbuf, Tn, Dn, Dn);
  }
  ln_kernel<1><<<Tn, 256, 0, stream>>>(xbuf, fln_s, fln_b, out);
}